// Round 12
// baseline (300.548 us; speedup 1.0000x reference)
//
#include <hip/hip_runtime.h>
#include <cstdint>

#define S_LEN 2048
#define NBATCH 2
#define NHEAD 16
#define E3 3072
#define EDIM 1024
#define DDIM 1024

typedef __attribute__((ext_vector_type(8))) short bf8;
typedef __attribute__((ext_vector_type(4))) float f4;

#define MFMA16(A, B, C) __builtin_amdgcn_mfma_f32_16x16x32_bf16(A, B, C, 0, 0, 0)

__device__ __forceinline__ ushort bf16rn(float f) {
    unsigned u = __builtin_bit_cast(unsigned, f);
    return (ushort)((u + 0x7fffu + ((u >> 16) & 1u)) >> 16);
}

// global -> LDS direct DMA, 16B per lane (linear dest; source pre-swizzled).
__device__ __forceinline__ void gload_lds16(const ushort* g, ushort* l) {
    __builtin_amdgcn_global_load_lds(
        (const __attribute__((address_space(1))) void*)g,
        (__attribute__((address_space(3))) void*)l, 16, 0, 0);
}

// ---------------------------------------------------------------------------
// Prep 1: cast f32 -> bf16 plane (RN).
// ---------------------------------------------------------------------------
__global__ __launch_bounds__(256) void cast_plane(
    const float* __restrict__ X, ushort* __restrict__ Xh, int n)
{
    const int i = (blockIdx.x * 256 + threadIdx.x) * 4;
    if (i >= n) return;
    float4 v = *(const float4*)&X[i];
    ushort4 h;
    h.x = bf16rn(v.x); h.y = bf16rn(v.y); h.z = bf16rn(v.z); h.w = bf16rn(v.w);
    *(ushort4*)&Xh[i] = h;
}

// ---------------------------------------------------------------------------
// Prep 2: W [K][N] f32 -> transposed bf16 plane [N][K].
// ---------------------------------------------------------------------------
__global__ __launch_bounds__(256) void transpose_cast(
    const float* __restrict__ W, ushort* __restrict__ Th, int K, int N)
{
    __shared__ float tile[32][33];
    const int t  = threadIdx.x;
    const int n0 = blockIdx.x << 5, k0 = blockIdx.y << 5;
    const int c  = t & 31, r = t >> 5;
    #pragma unroll
    for (int i = 0; i < 4; ++i)
        tile[c][r + (i << 3)] = W[(size_t)(k0 + r + (i << 3)) * N + n0 + c];
    __syncthreads();
    #pragma unroll
    for (int i = 0; i < 4; ++i)
        Th[(size_t)(n0 + r + (i << 3)) * K + k0 + c] = bf16rn(tile[r + (i << 3)][c]);
}

// ---------------------------------------------------------------------------
// Plain bf16 MFMA GEMM, 128x128 tile, BK=64, 512 thr = 8 waves (2x4 of 64x32).
// global_load_lds staging with source-side XOR swizzle; XCD-chunked swizzle.
// MODE 0: C -> bf16 (bias; Q cols (c%192<64) scaled 0.125).
// MODE 1: C -> f32 nontemporal (bias).
// ---------------------------------------------------------------------------
template<int MODE>
__global__ __launch_bounds__(512, 4) void gemm_bf16(
    const ushort* __restrict__ Ah, const ushort* __restrict__ Bh,
    const float* __restrict__ bias,
    float* __restrict__ Cf, ushort* __restrict__ Ch,
    int M, int N, int K)
{
    __shared__ ushort As[128][64];
    __shared__ ushort Bs[128][64];

    const int t    = threadIdx.x;
    const int lane = t & 63;
    const int w    = t >> 6;
    const int lo   = lane & 15, hi = lane >> 4;
    const int wr   = w >> 2;
    const int wc   = w & 3;

    const int nwg  = gridDim.x * gridDim.y;
    const int orig = blockIdx.x + blockIdx.y * gridDim.x;
    const int wgid = (orig & 7) * (nwg >> 3) + (orig >> 3);
    const int rb   = (wgid / gridDim.x) << 7;
    const int cb   = (wgid % gridDim.x) << 7;

    const int lrow = lane >> 3;
    const int scol = ((lane & 7) ^ lrow) << 3;
    const int w8   = w << 1;
    const int rsw  = (lo & 7) << 3;

    f4 acc[4][2] = {};

    for (int k0 = 0; k0 < K; k0 += 64) {
        __syncthreads();
        #pragma unroll
        for (int i = 0; i < 2; ++i) {
            const int r0  = (w8 + i) << 3;
            const int row = r0 + lrow;
            gload_lds16(&Ah[(size_t)(rb + row) * K + k0 + scol], &As[r0][0]);
            gload_lds16(&Bh[(size_t)(cb + row) * K + k0 + scol], &Bs[r0][0]);
        }
        __syncthreads();

        __builtin_amdgcn_s_setprio(1);
        #pragma unroll
        for (int st = 0; st < 2; ++st) {
            const int kc = ((st << 5) + (hi << 3)) ^ rsw;
            bf8 a[4], bfr[2];
            #pragma unroll
            for (int f = 0; f < 4; ++f)
                a[f] = *(const bf8*)&As[(wr << 6) + (f << 4) + lo][kc];
            #pragma unroll
            for (int g = 0; g < 2; ++g)
                bfr[g] = *(const bf8*)&Bs[(wc << 5) + (g << 4) + lo][kc];
            #pragma unroll
            for (int f = 0; f < 4; ++f)
                #pragma unroll
                for (int g = 0; g < 2; ++g)
                    acc[f][g] = MFMA16(a[f], bfr[g], acc[f][g]);
        }
        __builtin_amdgcn_s_setprio(0);
    }

    #pragma unroll
    for (int f = 0; f < 4; ++f) {
        #pragma unroll
        for (int g = 0; g < 2; ++g) {
            const int c  = cb + (wc << 5) + (g << 4) + lo;
            const float bv = bias[c];
            const float qs = (MODE == 0 && (c % 192) < 64) ? 0.125f : 1.0f;
            #pragma unroll
            for (int j = 0; j < 4; ++j) {
                const size_t row = (size_t)rb + (wr << 6) + (f << 4) + (hi << 2) + j;
                float v = (acc[f][g][j] + bv) * qs;
                if constexpr (MODE == 0) {
                    Ch[row * N + c] = bf16rn(v);
                } else {
                    __builtin_nontemporal_store(v, &Cf[row * N + c]);
                }
            }
        }
    }
}

// ---------------------------------------------------------------------------
// Fused attention, single-bf16 QK^T, double-buffered pipeline with COUNTED
// vmcnt barriers in pass 2 (T4): s_waitcnt vmcnt(4) retires the K-gload_lds
// + 8 V loads (oldest) while the 4 newest nontemporal attention stores stay
// in flight across the barrier -> no HBM store-ack drain per tile.
// 1-D grid, id = qblk*32 + bh => XCD = bh%8 (K/V L2 affinity).
// ---------------------------------------------------------------------------
__global__ __launch_bounds__(512) void attn_fused(
    const ushort* __restrict__ qh,
    float* __restrict__ attn, ushort* __restrict__ oh)
{
    __shared__ ushort ksh_h[2][64][64];
    __shared__ ushort vth[2][64][72];    // V^T: [d][k]
    __shared__ ushort plds[8][16][72];   // per-wave p: [q][k]

    const int t    = threadIdx.x;
    const int lane = t & 63;
    const int wv   = t >> 6;
    const int lo   = lane & 15, hi = lane >> 4;
    const int bh   = blockIdx.x & 31;          // XCD affinity: bh%8
    const int qblk = blockIdx.x >> 5;
    const int b    = bh >> 4, h = bh & 15;
    const size_t base = (size_t)b * S_LEN * E3 + h * 192;
    const int q0   = (qblk << 7) + (wv << 4);

    const int lrow = lane >> 3;
    const int scol = ((lane & 7) ^ lrow) << 3;
    const int r0k  = wv << 3;
    const int rsw  = (lo & 7) << 3;
    const int vd   = t & 63;

    bf8 qfh[2];
    #pragma unroll
    for (int st = 0; st < 2; ++st) {
        const size_t off = base + (size_t)(q0 + lo) * E3 + (st << 5) + (hi << 3);
        qfh[st] = *(const bf8*)&qh[off];
    }

    ushort4 vr[2];

    auto issueK = [&](int kt, int buf) {
        const size_t g = base + 64 + (size_t)(kt + r0k + lrow) * E3 + scol;
        gload_lds16(&qh[g], &ksh_h[buf][r0k][0]);
    };
    auto loadV = [&](int kt) {
        #pragma unroll
        for (int i = 0; i < 2; ++i) {
            const int k4 = ((t >> 6) + (i << 3)) << 2;
            ushort4 v;
            #pragma unroll
            for (int m = 0; m < 4; ++m)
                ((ushort*)&v)[m] = qh[base + 128 + (size_t)(kt + k4 + m) * E3 + vd];
            vr[i] = v;
        }
    };
    auto writeV = [&](int buf) {
        #pragma unroll
        for (int i = 0; i < 2; ++i)
            *(ushort4*)&vth[buf][vd][((t >> 6) + (i << 3)) << 2] = vr[i];
    };

    // ---- pass 1: denominators (K double-buffered; plain barriers: only the
    //      single prefetch gload is outstanding, drain cost is small)
    issueK(0, 0);
    __syncthreads();
    float ssum = 0.0f;
    for (int kt = 0; kt < S_LEN; kt += 64) {
        const int buf = (kt >> 6) & 1;
        if (kt + 64 < S_LEN) issueK(kt + 64, buf ^ 1);
        __builtin_amdgcn_s_setprio(1);
        #pragma unroll
        for (int sub = 0; sub < 4; ++sub) {
            f4 acc = {};
            #pragma unroll
            for (int st = 0; st < 2; ++st) {
                const int kc = ((st << 5) + (hi << 3)) ^ rsw;
                bf8 kh = *(const bf8*)&ksh_h[buf][(sub << 4) + lo][kc];
                acc = MFMA16(kh, qfh[st], acc);
            }
            #pragma unroll
            for (int j = 0; j < 4; ++j) ssum += __expf(acc[j]);
        }
        __builtin_amdgcn_s_setprio(0);
        __syncthreads();
    }
    ssum += __shfl_xor(ssum, 16, 64);
    ssum += __shfl_xor(ssum, 32, 64);
    const float inv_s = 1.0f / ssum;

    // ---- pass 2: attention write + PV (counted-vmcnt barriers)
    issueK(0, 0);
    loadV(0);
    writeV(0);                // compiler inserts the needed vmcnt for vr
    __syncthreads();          // prologue full drain ok (no stores yet)
    f4 oacc[4] = {};
    for (int kt = 0; kt < S_LEN; kt += 64) {
        const int buf = (kt >> 6) & 1;
        const bool pf = (kt + 64 < S_LEN);
        if (pf) { issueK(kt + 64, buf ^ 1); loadV(kt + 64); }
        __builtin_amdgcn_sched_barrier(0);   // pin vmem issue point

        #pragma unroll
        for (int sub = 0; sub < 4; ++sub) {
            f4 acc = {};
            __builtin_amdgcn_s_setprio(1);
            #pragma unroll
            for (int st = 0; st < 2; ++st) {
                const int kc = ((st << 5) + (hi << 3)) ^ rsw;
                bf8 kh = *(const bf8*)&ksh_h[buf][(sub << 4) + lo][kc];
                acc = MFMA16(kh, qfh[st], acc);
            }
            __builtin_amdgcn_s_setprio(0);
            f4 pw; ushort4 pb;
            #pragma unroll
            for (int j = 0; j < 4; ++j) {
                float p = __expf(acc[j]) * inv_s;
                pw[j] = p;
                ((ushort*)&pb)[j] = bf16rn(p);
            }
            __builtin_nontemporal_store(pw,
                (f4*)&attn[((size_t)bh * S_LEN + q0 + lo) * S_LEN +
                           kt + (sub << 4) + (hi << 2)]);
            *(ushort4*)&plds[wv][lo][(sub << 4) + (hi << 2)] = pb;
        }
        // PV: o += p @ V
        __builtin_amdgcn_s_setprio(1);
        #pragma unroll
        for (int kk = 0; kk < 2; ++kk) {
            bf8 pa = *(const bf8*)&plds[wv][lo][(kk << 5) + (hi << 3)];
            #pragma unroll
            for (int dt = 0; dt < 4; ++dt) {
                bf8 vb = *(const bf8*)&vth[buf][(dt << 4) + lo][(kk << 5) + (hi << 3)];
                oacc[dt] = MFMA16(pa, vb, oacc[dt]);
            }
        }
        __builtin_amdgcn_s_setprio(0);

        if (pf) {
            // Retire K-gload_lds(kt+64) + 8 V loads (oldest); leave the 4
            // newest attention stores in flight across the barrier.
            asm volatile("s_waitcnt vmcnt(4)" ::: "memory");
            __builtin_amdgcn_sched_barrier(0);
            writeV(buf ^ 1);
            asm volatile("s_waitcnt lgkmcnt(0)" ::: "memory");
            __builtin_amdgcn_sched_barrier(0);
            __builtin_amdgcn_s_barrier();
            __builtin_amdgcn_sched_barrier(0);
        }
    }

    // epilogue: o head -> bf16
    #pragma unroll
    for (int dt = 0; dt < 4; ++dt) {
        #pragma unroll
        for (int j = 0; j < 4; ++j) {
            const size_t row = (size_t)b * S_LEN + q0 + (hi << 2) + j;
            oh[row * EDIM + h * 64 + (dt << 4) + lo] = bf16rn(oacc[dt][j]);
        }
    }
}

// ---------------------------------------------------------------------------
extern "C" void kernel_launch(void* const* d_in, const int* in_sizes, int n_in,
                              void* d_out, int out_size, void* d_ws, size_t ws_size,
                              hipStream_t stream)
{
    const float* x    = (const float*)d_in[0];
    const float* Wqkv = (const float*)d_in[1];
    const float* bqkv = (const float*)d_in[2];
    const float* Wout = (const float*)d_in[3];
    const float* bout = (const float*)d_in[4];

    float* o_out    = (float*)d_out;
    float* attn_out = o_out + (size_t)NBATCH * S_LEN * DDIM;

    const size_t nQKV = (size_t)NBATCH * S_LEN * E3;
    const size_t nO   = (size_t)NBATCH * S_LEN * EDIM;
    const size_t nWq  = (size_t)DDIM * E3;

    ushort* qh    = (ushort*)d_ws;        // qkv bf16
    ushort* oh    = qh + nQKV;            // o-head bf16 (xh overlay before attn)
    ushort* wqt_h = oh + nO;
    ushort* wot_h = wqt_h + nWq;

    ushort* xh = oh;   // x bf16, dead after gemm1

    const int M = NBATCH * S_LEN;  // 4096

    cast_plane<<<(int)(nO / 1024), 256, 0, stream>>>(x, xh, (int)nO);
    transpose_cast<<<dim3(E3 / 32, DDIM / 32), 256, 0, stream>>>(Wqkv, wqt_h, DDIM, E3);
    transpose_cast<<<dim3(DDIM / 32, EDIM / 32), 256, 0, stream>>>(Wout, wot_h, EDIM, DDIM);

    // K1: qkv = x @ Wqkv + bqkv (bf16, Q pre-scaled 0.125)
    gemm_bf16<0><<<dim3(E3 / 128, M / 128), 512, 0, stream>>>(
        xh, wqt_h, bqkv, nullptr, qh, M, E3, DDIM);

    // K2: fused attention
    attn_fused<<<(S_LEN / 128) * NBATCH * NHEAD, 512, 0, stream>>>(
        qh, attn_out, oh);

    // K3: o = o_head @ Wout + bout (bf16, f32 out)
    gemm_bf16<1><<<dim3(DDIM / 128, M / 128), 512, 0, stream>>>(
        oh, wot_h, bout, o_out, nullptr, M, DDIM, EDIM);
}